// Round 6
// baseline (1313.302 us; speedup 1.0000x reference)
//
#include <hip/hip_runtime.h>
#include <hip/hip_bf16.h>
#include <stdint.h>

// EPLB router: LN -> fused [router+balance] MLP -> softmax/top2/EMA.
// Round 6 (= round 5 resubmit after infra failure): K-loop read-ahead pipeline
// (reads issued one MFMA-quad ahead, 1 barrier/tile, counted vmcnt(6));
// explicit lgkmcnt(0) before the per-tile barrier (free; reads provably drained);
// fused weight-prep kernel; wave-per-row LayerNorm.

#define TOKENS 16384
#define HDIM   2048
#define N1     3072
#define NEXP   64
#define NPART  24            // N1/128 n-blocks -> logit partials
#define LO_SCALE 2048.0f
#define INV_LO_SCALE (1.0f/2048.0f)

typedef _Float16 half8 __attribute__((ext_vector_type(8)));
typedef _Float16 half4 __attribute__((ext_vector_type(4)));
typedef float f32x4 __attribute__((ext_vector_type(4)));

__device__ __forceinline__ void gl_lds16(const void* g, void* l) {
  __builtin_amdgcn_global_load_lds((__attribute__((address_space(1))) void*)(g),
                                   (__attribute__((address_space(3))) void*)(l),
                                   16, 0, 0);
}

__device__ __forceinline__ f32x4 mfma16(half8 a, half8 b, f32x4 c) {
  return __builtin_amdgcn_mfma_f32_16x16x32_f16(a, b, c, 0, 0, 0);
}

__device__ __forceinline__ void split_f32(float v, _Float16& hi, _Float16& lo) {
  hi = (_Float16)v;
  lo = (_Float16)((v - (float)hi) * LO_SCALE);
}

// ---------------- fused weight prep: 4 transposes + bias combine + gld zero.
// Region map over flat blockIdx.x (256 threads each):
//   [0,4096)      w1   2048x2048 -> w1t rows 0..2047
//   [4096,6144)   lw1  2048x1024 -> w1t rows 2048..3071
//   [6144,6272)   w2   2048x64   -> w2t
//   [6272,6336)   lw2  1024x64   -> w2t cols +2048, scale .01
//   [6336,6349)   bias combine
//   6349          gld zero
__global__ __launch_bounds__(256) void prep_k(
    const float* __restrict__ w1, const float* __restrict__ lw1,
    const float* __restrict__ w2, const float* __restrict__ lw2,
    const float* __restrict__ b1, const float* __restrict__ lb1,
    const float* __restrict__ b2, const float* __restrict__ lb2,
    _Float16* __restrict__ w1th, _Float16* __restrict__ w1tl,
    _Float16* __restrict__ w2th, _Float16* __restrict__ w2tl,
    float* __restrict__ b1c, float* __restrict__ b2c, float* __restrict__ gld)
{
  const int bid = blockIdx.x, tid = threadIdx.x;
  if (bid >= 6336) {
    if (bid == 6349) { if (tid < 64) gld[tid] = 0.0f; return; }
    const int i = (bid - 6336) * 256 + tid;
    if (i < 2048)      b1c[i] = b1[i];
    else if (i < 3072) b1c[i] = lb1[i - 2048];
    else if (i < 3136) { const int e = i - 3072; b2c[e] = b2[e] + 0.01f * lb2[e]; }
    return;
  }
  const float* src; _Float16 *dh, *dl;
  int src_ld, dst_ld, row_off, col_off, rblk, cblk; float scale;
  if (bid < 4096) {
    src = w1;  dh = w1th; dl = w1tl; src_ld = 2048; dst_ld = 2048;
    row_off = 0; col_off = 0; scale = 1.0f; rblk = bid & 63; cblk = bid >> 6;
  } else if (bid < 6144) {
    const int idx = bid - 4096;
    src = lw1; dh = w1th; dl = w1tl; src_ld = 1024; dst_ld = 2048;
    row_off = 2048; col_off = 0; scale = 1.0f; rblk = idx & 63; cblk = idx >> 6;
  } else if (bid < 6272) {
    const int idx = bid - 6144;
    src = w2;  dh = w2th; dl = w2tl; src_ld = 64; dst_ld = 3072;
    row_off = 0; col_off = 0; scale = 1.0f; rblk = idx & 63; cblk = idx >> 6;
  } else {
    const int idx = bid - 6272;
    src = lw2; dh = w2th; dl = w2tl; src_ld = 64; dst_ld = 3072;
    row_off = 0; col_off = 2048; scale = 0.01f; rblk = idx & 31; cblk = idx >> 5;
  }
  __shared__ float tile[32][33];
  const int tx = tid & 31, ty = tid >> 5;
  const int r0 = rblk * 32, c0 = cblk * 32;
#pragma unroll
  for (int i = 0; i < 4; i++)
    tile[ty + i*8][tx] = src[(size_t)(r0 + ty + i*8) * src_ld + c0 + tx];
  __syncthreads();
#pragma unroll
  for (int i = 0; i < 4; i++) {
    const int c = c0 + ty + i*8;
    const int r = r0 + tx;
    const float v = tile[tx][ty + i*8] * scale;
    _Float16 h, l;
    split_f32(v, h, l);
    const size_t o = (size_t)(c + row_off) * dst_ld + (r + col_off);
    dh[o] = h; dl[o] = l;
  }
}

// ---------------- LayerNorm + f16 hi/lo split store. One wave per row.
__global__ __launch_bounds__(256) void ln_split_k(
    const float* __restrict__ x, const float* __restrict__ gamma, const float* __restrict__ beta,
    _Float16* __restrict__ xh, _Float16* __restrict__ xl)
{
  const int row = blockIdx.x * 4 + (threadIdx.x >> 6);
  const int l = threadIdx.x & 63;
  const float* xr = x + (size_t)row * HDIM;
  float4 v[8];
#pragma unroll
  for (int j = 0; j < 8; j++) v[j] = ((const float4*)xr)[l + j*64];
  float s = 0.0f;
#pragma unroll
  for (int j = 0; j < 8; j++) s += v[j].x + v[j].y + v[j].z + v[j].w;
  for (int off = 1; off < 64; off <<= 1) s += __shfl_xor(s, off);
  const float mu = s * (1.0f / HDIM);
  float q = 0.0f;
#pragma unroll
  for (int j = 0; j < 8; j++) {
    const float d0 = v[j].x - mu, d1 = v[j].y - mu, d2 = v[j].z - mu, d3 = v[j].w - mu;
    q += d0*d0 + d1*d1 + d2*d2 + d3*d3;
  }
  for (int off = 1; off < 64; off <<= 1) q += __shfl_xor(q, off);
  const float rsig = 1.0f / sqrtf(q * (1.0f / HDIM) + 1e-5f);
#pragma unroll
  for (int j = 0; j < 8; j++) {
    const float4 g4 = ((const float4*)gamma)[l + j*64];
    const float4 b4 = ((const float4*)beta)[l + j*64];
    const float xn[4] = {(v[j].x - mu)*rsig*g4.x + b4.x, (v[j].y - mu)*rsig*g4.y + b4.y,
                         (v[j].z - mu)*rsig*g4.z + b4.z, (v[j].w - mu)*rsig*g4.w + b4.w};
    half4 hv, lv;
#pragma unroll
    for (int k = 0; k < 4; k++) { _Float16 hi, lo; split_f32(xn[k], hi, lo); hv[k] = hi; lv[k] = lo; }
    *(half4*)&xh[(size_t)row * HDIM + (l + j*64)*4] = hv;
    *(half4*)&xl[(size_t)row * HDIM + (l + j*64)*4] = lv;
  }
}

// ---------------- GEMM1 fused, read-ahead pipelined K-loop.
// 256x128 tile, BK=32, 8 waves each 64x64 (4x2 grid). 3 LDS bufs (48KB each).
// Per K-tile: {rd B23 | MFMA q0} {rd A23 | MFMA q1} {stage t+2 | MFMA q2}
// {lgkmcnt(0); vmcnt(6); barrier; rd next A01B01 | MFMA q3}.
#define BUFB 49152

__global__ __launch_bounds__(512, 2) void gemm1_fused_k(
    const _Float16* __restrict__ xh, const _Float16* __restrict__ xl,
    const _Float16* __restrict__ w1th, const _Float16* __restrict__ w1tl,
    const _Float16* __restrict__ w2th, const _Float16* __restrict__ w2tl,
    const float* __restrict__ b1c, float* __restrict__ Lp)
{
  extern __shared__ char smem[];
  const int tid = threadIdx.x;
  const int i = tid & 63, w = tid >> 6;
  const int bid = blockIdx.x;
  // n-major XCD swizzle: XCD x owns nblk {3x..3x+2} (L2-resident W1 slice), iterates m.
  const int xcd = bid & 7, loc = bid >> 3;
  const int nblk = xcd * 3 + (loc % 3), mblk = loc / 3;
  const int m0 = mblk * 256, n0 = nblk * 128;

  const int g = w >> 1;        // row group 0..3 (64 rows)
  const int ch = w & 1;        // col half 0..1 (64 cols)
  const int wr = g * 64, wc = ch * 64;

  // --- staging sources: pre-swizzled global addresses, linear LDS dests
  const _Float16* srcA[4]; int ldsA[4];
  const _Float16* srcB[2]; int ldsB[2];
#pragma unroll
  for (int j = 0; j < 4; j++) {
    const int r = (w*4 + j)*8 + (i >> 3);
    const int s = (i & 7) ^ (r & 7);
    srcA[j] = (s < 4 ? xh : xl) + (size_t)(m0 + r) * HDIM + (s & 3) * 8;
    ldsA[j] = (w*4 + j) * 1024;
  }
#pragma unroll
  for (int j = 0; j < 2; j++) {
    const int r = (w*2 + j)*8 + (i >> 3);
    const int s = (i & 7) ^ (r & 7);
    srcB[j] = (s < 4 ? w1th : w1tl) + (size_t)(n0 + r) * HDIM + (s & 3) * 8;
    ldsB[j] = 32768 + (w*2 + j) * 1024;
  }

  // --- fragment read offsets
  const int aoff = (wr + (i & 15))*128 + (((i >> 4) ^ (i & 7)) << 4);
  const int boff = 32768 + (wc + (i & 15))*128 + (((i >> 4) ^ (i & 7)) << 4);

  f32x4 am[4][4] = {{{0}}};
  f32x4 ac[4][4] = {{{0}}};
  half8 afh[4], afl[4], bfh[4], bfl[4];

#define STG_ALL(BUF, KT) { char* _b = smem + (BUF)*BUFB; \
    gl_lds16(srcA[0] + (KT), _b + ldsA[0]); \
    gl_lds16(srcA[1] + (KT), _b + ldsA[1]); \
    gl_lds16(srcA[2] + (KT), _b + ldsA[2]); \
    gl_lds16(srcA[3] + (KT), _b + ldsA[3]); \
    gl_lds16(srcB[0] + (KT), _b + ldsB[0]); \
    gl_lds16(srcB[1] + (KT), _b + ldsB[1]); }

#define LDFB(BUF, off) (*(const half8*)(smem + (BUF)*BUFB + (off)))

#define RD_A01(BUF) { \
    afh[0] = LDFB(BUF, aoff);          afl[0] = LDFB(BUF, aoff ^ 64); \
    afh[1] = LDFB(BUF, aoff + 2048);   afl[1] = LDFB(BUF, (aoff + 2048) ^ 64); }
#define RD_B01(BUF) { \
    bfh[0] = LDFB(BUF, boff);          bfl[0] = LDFB(BUF, boff ^ 64); \
    bfh[1] = LDFB(BUF, boff + 2048);   bfl[1] = LDFB(BUF, (boff + 2048) ^ 64); }
#define RD_B23(BUF) { \
    bfh[2] = LDFB(BUF, boff + 4096);   bfl[2] = LDFB(BUF, (boff + 4096) ^ 64); \
    bfh[3] = LDFB(BUF, boff + 6144);   bfl[3] = LDFB(BUF, (boff + 6144) ^ 64); }
#define RD_A23(BUF) { \
    afh[2] = LDFB(BUF, aoff + 4096);   afl[2] = LDFB(BUF, (aoff + 4096) ^ 64); \
    afh[3] = LDFB(BUF, aoff + 6144);   afl[3] = LDFB(BUF, (aoff + 6144) ^ 64); }

#define MM3(M, N) { \
    am[M][N] = mfma16(afh[M], bfh[N], am[M][N]); \
    ac[M][N] = mfma16(afl[M], bfh[N], ac[M][N]); \
    ac[M][N] = mfma16(afh[M], bfl[N], ac[M][N]); }

#define QUAD(MA, MB, NA, NB) { \
    __builtin_amdgcn_s_setprio(1); \
    MM3(MA, NA) MM3(MA, NB) MM3(MB, NA) MM3(MB, NB) \
    __builtin_amdgcn_s_setprio(0); \
    __builtin_amdgcn_sched_barrier(0); }

// One K-tile. On entry: A01/B01 regs for BUF loaded (boundary of prev tile).
// All ds_reads of BUF are consumed by q0-q2 MFMAs, so lgkmcnt(0) before the
// barrier is free and guarantees no outstanding reads cross it (stage-WAR safe).
#define TILE(BUF, SBUF, SKT, DOSTAGE, VMS, DONEXT, NBUF) { \
    RD_B23(BUF) \
    __builtin_amdgcn_sched_barrier(0); \
    QUAD(0, 1, 0, 1)                      /* q0: A01 x B01 */ \
    RD_A23(BUF) \
    __builtin_amdgcn_sched_barrier(0); \
    QUAD(0, 1, 2, 3)                      /* q1: A01 x B23 */ \
    if (DOSTAGE) STG_ALL(SBUF, SKT); \
    __builtin_amdgcn_sched_barrier(0); \
    QUAD(2, 3, 0, 1)                      /* q2: A23 x B01 */ \
    asm volatile("s_waitcnt lgkmcnt(0)" ::: "memory"); \
    asm volatile("s_waitcnt vmcnt(" VMS ")" ::: "memory"); \
    __builtin_amdgcn_s_barrier(); \
    if (DONEXT) { RD_A01(NBUF) RD_B01(NBUF) } \
    __builtin_amdgcn_sched_barrier(0); \
    QUAD(2, 3, 2, 3)                      /* q3: A23 x B23 */ }

  // prologue: stage tiles 0,1; wait tile0; preload its A01/B01
  STG_ALL(0, 0)
  STG_ALL(1, 32)
  asm volatile("s_waitcnt vmcnt(6)" ::: "memory");
  __builtin_amdgcn_s_barrier();
  RD_A01(0) RD_B01(0)
  __builtin_amdgcn_sched_barrier(0);

  for (int u = 0; u < 20; u++) {
    const int kt = (3*u + 2) * 32;
    TILE(0, 2, kt,      1, "6", 1, 1)
    TILE(1, 0, kt + 32, 1, "6", 1, 2)
    TILE(2, 1, kt + 64, 1, "6", 1, 0)
  }
  TILE(0, 2, 62*32, 1, "6", 1, 1)   // t=60 stages 62
  TILE(1, 0, 63*32, 1, "6", 1, 2)   // t=61 stages 63
  TILE(2, 0, 0,     0, "0", 1, 0)   // t=62
  TILE(0, 0, 0,     0, "0", 0, 0)   // t=63
#undef TILE
#undef QUAD
#undef MM3
#undef RD_A01
#undef RD_B01
#undef RD_A23
#undef RD_B23
#undef LDFB
#undef STG_ALL

  __builtin_amdgcn_s_barrier();   // K-loop LDS reads done before epilogue overwrites

  // ---- epilogue: h = relu(am + ac/2048 + b1), split, LDS transpose (packed u32).
  float bv[4];
#pragma unroll
  for (int n = 0; n < 4; n++) bv[n] = b1c[n0 + wc + n*16 + (i & 15)];

  char* hwg = smem + g * 32768;   // 64 rows x 128 cells x 4B per row-group
#pragma unroll
  for (int m = 0; m < 4; m++)
#pragma unroll
    for (int n = 0; n < 4; n++)
#pragma unroll
      for (int r = 0; r < 4; r++) {
        const int lr = m*16 + (i >> 4)*4 + r;
        const int lc = wc + n*16 + (i & 15);
        float v = am[m][n][r] + ac[m][n][r] * INV_LO_SCALE + bv[n];
        v = fmaxf(v, 0.0f);
        _Float16 hh, ll;
        split_f32(v, hh, ll);
        const uint32_t pk = (uint32_t)__builtin_bit_cast(unsigned short, hh) |
                            ((uint32_t)__builtin_bit_cast(unsigned short, ll) << 16);
        const int pc = lc ^ ((lr & 3) << 2) ^ (((lr >> 2) & 3) << 4);
        *(uint32_t*)(hwg + lr*512 + pc*4) = pk;
      }
  asm volatile("s_waitcnt lgkmcnt(0)" ::: "memory");
  __builtin_amdgcn_s_barrier();                 // pair writes both col halves
  __builtin_amdgcn_sched_barrier(0);

  // ---- fused GEMM2: group rows (64) x K=128 vs W2c experts [ch*32, ch*32+32)
  f32x4 la[4][2] = {{{0}}};
  f32x4 lc2[4][2] = {{{0}}};
#pragma unroll
  for (int ks = 0; ks < 4; ks++) {
    half8 wh[2], wl[2];
#pragma unroll
    for (int e = 0; e < 2; e++) {
      const size_t wo = (size_t)(ch*32 + e*16 + (i & 15)) * N1 + n0 + ks*32 + ((i >> 4) << 3);
      wh[e] = *(const half8*)(w2th + wo);
      wl[e] = *(const half8*)(w2tl + wo);
    }
#pragma unroll
    for (int m2 = 0; m2 < 4; m2++) {
      const int lr = m2*16 + (i & 15);
      const int c0 = ks*32 + ((i >> 4) << 3);
      const int x1 = ((lr & 3) << 2) ^ (((lr >> 2) & 3) << 4);
      const uint4 cl0 = *(const uint4*)(hwg + lr*512 + ((c0 ^ x1) << 2));
      const uint4 cl1 = *(const uint4*)(hwg + lr*512 + (((c0 + 4) ^ x1) << 2));
      const uint32_t cu[8] = {cl0.x, cl0.y, cl0.z, cl0.w, cl1.x, cl1.y, cl1.z, cl1.w};
      half8 pah, pal;
#pragma unroll
      for (int j = 0; j < 8; j++) {
        pah[j] = __builtin_bit_cast(_Float16, (unsigned short)(cu[j] & 0xffff));
        pal[j] = __builtin_bit_cast(_Float16, (unsigned short)(cu[j] >> 16));
      }
#pragma unroll
      for (int e = 0; e < 2; e++) {
        la[m2][e]  = mfma16(pah, wh[e], la[m2][e]);
        lc2[m2][e] = mfma16(pal, wh[e], lc2[m2][e]);
        lc2[m2][e] = mfma16(pah, wl[e], lc2[m2][e]);
      }
    }
  }

  float* lpb = Lp + ((size_t)nblk * TOKENS + m0 + wr) * NEXP;
#pragma unroll
  for (int m2 = 0; m2 < 4; m2++)
#pragma unroll
    for (int e = 0; e < 2; e++)
#pragma unroll
      for (int r = 0; r < 4; r++) {
        const int row = m2*16 + (i >> 4)*4 + r;
        const int col = ch*32 + e*16 + (i & 15);
        lpb[row*NEXP + col] = la[m2][e][r] + lc2[m2][e][r] * INV_LO_SCALE;
      }
}

// ---------------- softmax + top2 + outputs + per-expert prob sums. One wave per token.
__global__ __launch_bounds__(256) void softmax_topk_k(
    const float* __restrict__ Lp, const float* __restrict__ b2c,
    float* __restrict__ out, float* __restrict__ gloads)
{
  __shared__ float lred[4][64];
  const int tid = threadIdx.x, l = tid & 63, w = tid >> 6;
  const int tb = blockIdx.x * 16;
  const float bc = b2c[l];
  float psum = 0.0f;
#pragma unroll
  for (int it = 0; it < 4; it++) {
    const int t = tb + w*4 + it;
    const float* lp = Lp + (size_t)t * NEXP + l;
    float c = bc;
#pragma unroll
    for (int p = 0; p < NPART; p++) c += lp[(size_t)p * TOKENS * NEXP];
    float v1 = c; int i1 = l;
    for (int off = 1; off < 64; off <<= 1) {
      const float ov = __shfl_xor(v1, off);
      const int   oi = __shfl_xor(i1, off);
      if (ov > v1 || (ov == v1 && oi < i1)) { v1 = ov; i1 = oi; }
    }
    const float c2 = (l == i1) ? -3.0e38f : c;
    float v2 = c2; int i2 = l;
    for (int off = 1; off < 64; off <<= 1) {
      const float ov = __shfl_xor(v2, off);
      const int   oi = __shfl_xor(i2, off);
      if (ov > v2 || (ov == v2 && oi < i2)) { v2 = ov; i2 = oi; }
    }
    const float e = expf(c - v1);
    float Z = e;
    for (int off = 1; off < 64; off <<= 1) Z += __shfl_xor(Z, off);
    psum += e / Z;
    if (l == 0) {
      const float e2 = expf(v2 - v1);
      const float inv = 1.0f / (1.0f + e2);
      out[2*t]     = (float)i1;
      out[2*t + 1] = (float)i2;
      out[2*TOKENS + 2*t]     = inv;
      out[2*TOKENS + 2*t + 1] = e2 * inv;
    }
  }
  lred[w][l] = psum;
  __syncthreads();
  if (tid < 64)
    atomicAdd(&gloads[tid], lred[0][tid] + lred[1][tid] + lred[2][tid] + lred[3][tid]);
}

__global__ void finalize_k(const float* __restrict__ gloads, const float* __restrict__ eloads,
                           float* __restrict__ out)
{
  const int e = threadIdx.x;
  const float nl = 0.9f * eloads[e] + 0.1f * (gloads[e] * (1.0f / (float)TOKENS));
  float tot = nl;
  for (int off = 1; off < 64; off <<= 1) tot += __shfl_xor(tot, off);
  const float target = tot * (1.0f / (float)NEXP);
  const float d = nl - target;
  float aux = d * d;
  for (int off = 1; off < 64; off <<= 1) aux += __shfl_xor(aux, off);
  out[4*TOKENS + 1 + e] = nl;
  if (e == 0) out[4*TOKENS] = aux;
}

extern "C" void kernel_launch(void* const* d_in, const int* in_sizes, int n_in,
                              void* d_out, int out_size, void* d_ws, size_t ws_size,
                              hipStream_t stream)
{
  (void)in_sizes; (void)n_in; (void)out_size; (void)ws_size;
  const float* x      = (const float*)d_in[0];
  const float* gam    = (const float*)d_in[1];
  const float* bet    = (const float*)d_in[2];
  const float* w1     = (const float*)d_in[3];
  const float* b1     = (const float*)d_in[4];
  const float* w2     = (const float*)d_in[5];
  const float* b2     = (const float*)d_in[6];
  const float* lw1    = (const float*)d_in[7];
  const float* lb1    = (const float*)d_in[8];
  const float* lw2    = (const float*)d_in[9];
  const float* lb2    = (const float*)d_in[10];
  const float* eloads = (const float*)d_in[11];
  float* out = (float*)d_out;

  char* ws = (char*)d_ws;
  _Float16* xh   = (_Float16*)(ws + 0);            // 16384x2048 f16      67108864
  _Float16* xl   = (_Float16*)(ws + 67108864);     //                     67108864
  _Float16* w1th = (_Float16*)(ws + 134217728);    // 3072x2048 f16       12582912
  _Float16* w1tl = (_Float16*)(ws + 146800640);    //                     12582912
  _Float16* w2th = (_Float16*)(ws + 159383552);    // 64x3072 f16           393216
  _Float16* w2tl = (_Float16*)(ws + 159776768);    //                       393216
  float*    b1c  = (float*)   (ws + 160169984);    // 3072 f32               12288
  float*    b2c  = (float*)   (ws + 160182272);    // 64 f32                   256
  float*    Lp   = (float*)   (ws + 160182528);    // 24x16384x64 f32    100663296
  float*    gld  = (float*)   (ws + 260845824);    // 64 f32                   256

  prep_k<<<6350, 256, 0, stream>>>(w1, lw1, w2, lw2, b1, lb1, b2, lb2,
                                   w1th, w1tl, w2th, w2tl, b1c, b2c, gld);

  ln_split_k<<<TOKENS/4, 256, 0, stream>>>(x, gam, bet, xh, xl);

  hipFuncSetAttribute((const void*)gemm1_fused_k,
                      hipFuncAttributeMaxDynamicSharedMemorySize, 3 * BUFB);
  gemm1_fused_k<<<1536, 512, 3 * BUFB, stream>>>(xh, xl, w1th, w1tl, w2th, w2tl, b1c, Lp);

  softmax_topk_k<<<TOKENS/16, 256, 0, stream>>>(Lp, b2c, out, gld);
  finalize_k<<<1, 64, 0, stream>>>(gld, eloads, out);
}